// Round 2
// baseline (1215.443 us; speedup 1.0000x reference)
//
#include <hip/hip_runtime.h>

#define N_NODES 100000
#define N_EDGES 640000
#define D 128
#define NLAYERS 4

// ---------------- CSR build ----------------
__global__ void count_kernel(const int* __restrict__ edge, int* __restrict__ cnt) {
    int e = blockIdx.x * 256 + threadIdx.x;
    if (e < N_EDGES) {
        atomicAdd(&cnt[edge[N_EDGES + e]], 1);
    }
}

__global__ void scan_local(const int* __restrict__ cnt, int* __restrict__ rp,
                           int* __restrict__ bsum) {
    __shared__ int tsum[256];
    int t = threadIdx.x;
    int base = blockIdx.x * 1024 + t * 4;
    int v[4];
#pragma unroll
    for (int j = 0; j < 4; ++j) {
        int i = base + j;
        v[j] = (i < N_NODES) ? cnt[i] : 0;
    }
    int ts = v[0] + v[1] + v[2] + v[3];
    tsum[t] = ts;
    __syncthreads();
    for (int off = 1; off < 256; off <<= 1) {
        int add = (t >= off) ? tsum[t - off] : 0;
        __syncthreads();
        tsum[t] += add;
        __syncthreads();
    }
    int incl = tsum[t];
    int run = incl - ts;  // exclusive prefix for this thread
#pragma unroll
    for (int j = 0; j < 4; ++j) {
        int i = base + j;
        if (i < N_NODES) rp[i] = run;
        run += v[j];
    }
    if (t == 255) bsum[blockIdx.x] = incl;
}

__global__ void scan_bsums(int* __restrict__ bsum, int nblocks) {
    if (threadIdx.x == 0 && blockIdx.x == 0) {
        int run = 0;
        for (int b = 0; b < nblocks; ++b) {
            int v = bsum[b];
            bsum[b] = run;
            run += v;
        }
    }
}

__global__ void scan_add(int* __restrict__ rp, int* __restrict__ fill,
                         const int* __restrict__ bsum) {
    int add = bsum[blockIdx.x];
    int base = blockIdx.x * 1024;
#pragma unroll
    for (int j = 0; j < 4; ++j) {
        int i = base + j * 256 + threadIdx.x;
        if (i < N_NODES) {
            int v = rp[i] + add;
            rp[i] = v;
            fill[i] = v;
        }
    }
    if (blockIdx.x == 0 && threadIdx.x == 0) rp[N_NODES] = N_EDGES;
}

__global__ void fill_kernel(const int* __restrict__ edge, int* __restrict__ fill,
                            int* __restrict__ col) {
    int e = blockIdx.x * 256 + threadIdx.x;
    if (e < N_EDGES) {
        int dst = edge[N_EDGES + e];
        int slot = atomicAdd(&fill[dst], 1);
        col[slot] = edge[e];
    }
}

// ---------------- aggregation: S[v] = inv_deg * sum_{e: dst=v} h[src(e)] ----------------
__global__ __launch_bounds__(256) void agg_kernel(const float* __restrict__ h,
                                                  const int* __restrict__ rp,
                                                  const int* __restrict__ col,
                                                  float* __restrict__ S) {
    int w = threadIdx.x >> 6;
    int lane = threadIdx.x & 63;
    int v = blockIdx.x * 4 + w;
    if (v >= N_NODES) return;
    int beg = rp[v];
    int end = rp[v + 1];
    const float2* hp = (const float2*)h;
    float ax = 0.f, ay = 0.f;
    for (int j = beg; j < end; ++j) {
        int u = col[j];
        float2 t = hp[(size_t)u * 64 + lane];
        ax += t.x;
        ay += t.y;
    }
    float inv = 1.0f / fmaxf((float)(end - beg), 1.0f);
    float2 o;
    o.x = ax * inv;
    o.y = ay * inv;
    ((float2*)S)[(size_t)v * 64 + lane] = o;
}

// ---------------- fp32 GEMM, wave = 64 rows x 16 cols, W via scalar (SGPR) loads ----
// FUSED=0: out = A@W1^T + b1                                (input projection)
// FUSED=1: T = A@W1^T + b1*(cnt>0); out = Hin + relu(T@W2^T + b2)   (one GNN layer)
// A-tile (and T-tile) in LDS, XOR-swizzled (granule ^= row&7) for conflict-free
// ds_read_b128 at 512B row stride.
template <int FUSED>
__global__ __launch_bounds__(512, 4) void layer_k(const float* __restrict__ A,
                                                  const float* __restrict__ W1,
                                                  const float* __restrict__ b1,
                                                  const float* __restrict__ W2,
                                                  const float* __restrict__ b2,
                                                  const int* __restrict__ cnt,
                                                  const float* __restrict__ Hin,
                                                  float* __restrict__ out, int nrows) {
    __shared__ float4 As[64 * 32];
    __shared__ float4 Ts[FUSED ? 64 * 32 : 1];
    int t = threadIdx.x;
    int rowbase = blockIdx.x * 64;

    // stage A tile (coalesced global read, swizzled LDS write)
#pragma unroll
    for (int ch = 0; ch < 4; ++ch) {
        int flat = ch * 512 + t;  // 0..2047 float4 slots
        int r = flat >> 5;
        int g = flat & 31;
        int gr = rowbase + r;
        float4 a = (gr < nrows) ? ((const float4*)A)[(size_t)gr * 32 + g]
                                : make_float4(0.f, 0.f, 0.f, 0.f);
        As[r * 32 + (g ^ (r & 7))] = a;
    }
    __syncthreads();

    int lane = t & 63;
    int wid = __builtin_amdgcn_readfirstlane(t >> 6);  // 0..7, wave-uniform in SGPR
    int c0 = wid * 16;                                 // this wave's 16 output cols
    int r = lane;                                      // this lane's row in the tile
    int grow = rowbase + r;
    int rs = (r & 7);

    float acc[16];
#pragma unroll
    for (int c = 0; c < 16; ++c) acc[c] = 0.f;

    const float* W1p = W1 + c0 * 128;
#pragma unroll 2
    for (int k4 = 0; k4 < 32; ++k4) {
        float4 av = As[r * 32 + (k4 ^ rs)];
#pragma unroll
        for (int c = 0; c < 16; ++c) {
            const float* wr = W1p + c * 128 + k4 * 4;  // wave-uniform -> s_load
            acc[c] = fmaf(av.x, wr[0],
                          fmaf(av.y, wr[1], fmaf(av.z, wr[2], fmaf(av.w, wr[3], acc[c]))));
        }
    }

    if (FUSED) {
        float bf = (grow < nrows && cnt[grow] > 0) ? 1.0f : 0.0f;
#pragma unroll
        for (int j = 0; j < 4; ++j) {
            float4 tv;
            tv.x = fmaf(b1[c0 + 4 * j + 0], bf, acc[4 * j + 0]);
            tv.y = fmaf(b1[c0 + 4 * j + 1], bf, acc[4 * j + 1]);
            tv.z = fmaf(b1[c0 + 4 * j + 2], bf, acc[4 * j + 2]);
            tv.w = fmaf(b1[c0 + 4 * j + 3], bf, acc[4 * j + 3]);
            Ts[r * 32 + ((c0 / 4 + j) ^ rs)] = tv;
        }
        __syncthreads();

        float acc2[16];
#pragma unroll
        for (int c = 0; c < 16; ++c) acc2[c] = 0.f;
        const float* W2p = W2 + c0 * 128;
#pragma unroll 2
        for (int k4 = 0; k4 < 32; ++k4) {
            float4 av = Ts[r * 32 + (k4 ^ rs)];
#pragma unroll
            for (int c = 0; c < 16; ++c) {
                const float* wr = W2p + c * 128 + k4 * 4;
                acc2[c] = fmaf(av.x, wr[0],
                               fmaf(av.y, wr[1], fmaf(av.z, wr[2], fmaf(av.w, wr[3], acc2[c]))));
            }
        }
        if (grow < nrows) {
#pragma unroll
            for (int j = 0; j < 4; ++j) {
                float4 hv = ((const float4*)Hin)[(size_t)grow * 32 + c0 / 4 + j];
                float4 o;
                o.x = hv.x + fmaxf(acc2[4 * j + 0] + b2[c0 + 4 * j + 0], 0.f);
                o.y = hv.y + fmaxf(acc2[4 * j + 1] + b2[c0 + 4 * j + 1], 0.f);
                o.z = hv.z + fmaxf(acc2[4 * j + 2] + b2[c0 + 4 * j + 2], 0.f);
                o.w = hv.w + fmaxf(acc2[4 * j + 3] + b2[c0 + 4 * j + 3], 0.f);
                ((float4*)out)[(size_t)grow * 32 + c0 / 4 + j] = o;
            }
        }
    } else {
        if (grow < nrows) {
#pragma unroll
            for (int j = 0; j < 4; ++j) {
                float4 o;
                o.x = acc[4 * j + 0] + b1[c0 + 4 * j + 0];
                o.y = acc[4 * j + 1] + b1[c0 + 4 * j + 1];
                o.z = acc[4 * j + 2] + b1[c0 + 4 * j + 2];
                o.w = acc[4 * j + 3] + b1[c0 + 4 * j + 3];
                ((float4*)out)[(size_t)grow * 32 + c0 / 4 + j] = o;
            }
        }
    }
}

extern "C" void kernel_launch(void* const* d_in, const int* in_sizes, int n_in,
                              void* d_out, int out_size, void* d_ws, size_t ws_size,
                              hipStream_t stream) {
    const float* x = (const float*)d_in[0];
    const float* Wi = (const float*)d_in[1];
    const float* bi = (const float*)d_in[2];
    const float* Wm = (const float*)d_in[3];
    const float* bm = (const float*)d_in[4];
    const float* Wu = (const float*)d_in[5];
    const float* bu = (const float*)d_in[6];
    const int* edge = (const int*)d_in[7];
    float* h = (float*)d_out;

    // workspace layout (256B aligned)
    char* ws = (char*)d_ws;
    size_t off = 0;
    auto alloc = [&](size_t bytes) {
        void* p = ws + off;
        off += (bytes + 255) & ~(size_t)255;
        return p;
    };
    float* S = (float*)alloc((size_t)N_NODES * D * sizeof(float));
    int* cnt = (int*)alloc((size_t)N_NODES * sizeof(int));
    int* rp = (int*)alloc((size_t)(N_NODES + 1) * sizeof(int));
    int* fill = (int*)alloc((size_t)N_NODES * sizeof(int));
    int* bsum = (int*)alloc(1024 * sizeof(int));
    int* col = (int*)alloc((size_t)N_EDGES * sizeof(int));

    const int scan_blocks = (N_NODES + 1023) / 1024;  // 98
    const int edge_blocks = (N_EDGES + 255) / 256;    // 2500
    const int gemm_blocks = (N_NODES + 63) / 64;      // 1563
    const int agg_blocks = (N_NODES + 3) / 4;         // 25000

    // CSR build (per call; deterministic given inputs)
    hipMemsetAsync(cnt, 0, (size_t)N_NODES * sizeof(int), stream);
    count_kernel<<<edge_blocks, 256, 0, stream>>>(edge, cnt);
    scan_local<<<scan_blocks, 256, 0, stream>>>(cnt, rp, bsum);
    scan_bsums<<<1, 64, 0, stream>>>(bsum, scan_blocks);
    scan_add<<<scan_blocks, 256, 0, stream>>>(rp, fill, bsum);
    fill_kernel<<<edge_blocks, 256, 0, stream>>>(edge, fill, col);

    // input projection: h = x @ Wi^T + bi
    layer_k<0><<<gemm_blocks, 512, 0, stream>>>(x, Wi, bi, nullptr, nullptr, nullptr, nullptr, h,
                                                N_NODES);

    for (int l = 0; l < NLAYERS; ++l) {
        agg_kernel<<<agg_blocks, 256, 0, stream>>>(h, rp, col, S);
        layer_k<1><<<gemm_blocks, 512, 0, stream>>>(S, Wm + (size_t)l * D * D,
                                                    bm + (size_t)l * D, Wu + (size_t)l * D * D,
                                                    bu + (size_t)l * D, cnt, h, h, N_NODES);
    }
}

// Round 3
// 553.046 us; speedup vs baseline: 2.1977x; 2.1977x over previous
//
#include <hip/hip_runtime.h>

#define N_NODES 100000
#define N_EDGES 640000
#define D 128
#define NLAYERS 4

typedef __attribute__((ext_vector_type(8))) short short8;
typedef __attribute__((ext_vector_type(4))) float f32x4;

// f32 -> bf16 with round-to-nearest-even
__device__ __forceinline__ unsigned short cvbf(float f) {
    unsigned u = __float_as_uint(f);
    return (unsigned short)((u + 0x7fffu + ((u >> 16) & 1u)) >> 16);
}

// ---------------- CSR build ----------------
__global__ void count_kernel(const int* __restrict__ edge, int* __restrict__ cnt) {
    int e = blockIdx.x * 256 + threadIdx.x;
    if (e < N_EDGES) atomicAdd(&cnt[edge[N_EDGES + e]], 1);
}

__global__ void scan_local(const int* __restrict__ cnt, int* __restrict__ rp,
                           int* __restrict__ bsum) {
    __shared__ int tsum[256];
    int t = threadIdx.x;
    int base = blockIdx.x * 1024 + t * 4;
    int v[4];
#pragma unroll
    for (int j = 0; j < 4; ++j) {
        int i = base + j;
        v[j] = (i < N_NODES) ? cnt[i] : 0;
    }
    int ts = v[0] + v[1] + v[2] + v[3];
    tsum[t] = ts;
    __syncthreads();
    for (int off = 1; off < 256; off <<= 1) {
        int add = (t >= off) ? tsum[t - off] : 0;
        __syncthreads();
        tsum[t] += add;
        __syncthreads();
    }
    int incl = tsum[t];
    int run = incl - ts;
#pragma unroll
    for (int j = 0; j < 4; ++j) {
        int i = base + j;
        if (i < N_NODES) rp[i] = run;
        run += v[j];
    }
    if (t == 255) bsum[blockIdx.x] = incl;
}

__global__ void scan_bsums(int* __restrict__ bsum, int nblocks) {
    if (threadIdx.x == 0 && blockIdx.x == 0) {
        int run = 0;
        for (int b = 0; b < nblocks; ++b) {
            int v = bsum[b];
            bsum[b] = run;
            run += v;
        }
    }
}

__global__ void scan_add(int* __restrict__ rp, int* __restrict__ fill,
                         const int* __restrict__ bsum) {
    int add = bsum[blockIdx.x];
    int base = blockIdx.x * 1024;
#pragma unroll
    for (int j = 0; j < 4; ++j) {
        int i = base + j * 256 + threadIdx.x;
        if (i < N_NODES) {
            int v = rp[i] + add;
            rp[i] = v;
            fill[i] = v;
        }
    }
    if (blockIdx.x == 0 && threadIdx.x == 0) rp[N_NODES] = N_EDGES;
}

__global__ void fill_kernel(const int* __restrict__ edge, int* __restrict__ fill,
                            int* __restrict__ col) {
    int e = blockIdx.x * 256 + threadIdx.x;
    if (e < N_EDGES) {
        int dst = edge[N_EDGES + e];
        int slot = atomicAdd(&fill[dst], 1);
        col[slot] = edge[e];
    }
}

// ---------------- weight fp32 -> bf16 ----------------
__global__ void wconv(const float* __restrict__ in, unsigned short* __restrict__ out, int n4) {
    int i = blockIdx.x * 256 + threadIdx.x;
    if (i < n4) {
        float4 v = ((const float4*)in)[i];
        ushort4 o;
        o.x = cvbf(v.x);
        o.y = cvbf(v.y);
        o.z = cvbf(v.z);
        o.w = cvbf(v.w);
        ((ushort4*)out)[i] = o;
    }
}

// ---------------- aggregation (bf16 gather): S_bf[v] = inv_deg * sum h_bf[src] ------
__global__ __launch_bounds__(256) void agg_kernel(const unsigned* __restrict__ hb,
                                                  const int* __restrict__ rp,
                                                  const int* __restrict__ col,
                                                  unsigned* __restrict__ Sb) {
    int w = threadIdx.x >> 6;
    int lane = threadIdx.x & 63;
    int v = blockIdx.x * 4 + w;
    if (v >= N_NODES) return;
    int beg = rp[v];
    int end = rp[v + 1];
    float ax = 0.f, ay = 0.f;
    for (int j = beg; j < end; ++j) {
        int u = col[j];
        unsigned p = hb[(size_t)u * 64 + lane];  // 2 bf16 cols
        ax += __uint_as_float(p << 16);
        ay += __uint_as_float(p & 0xffff0000u);
    }
    float inv = 1.0f / fmaxf((float)(end - beg), 1.0f);
    ax *= inv;
    ay *= inv;
    Sb[(size_t)v * 64 + lane] = ((unsigned)cvbf(ay) << 16) | (unsigned)cvbf(ax);
}

// ---------------- MFMA layer kernel ----------------
// FUSED=0: outf = A@W1^T + b1 (+ bf16 mirror)
// FUSED=1: T = A@W1^T + b1*(cnt>0); outf = Hin + relu(T@W2^T + b2)  (+ bf16 mirror)
// Block: 64 rows, 256 threads (4 waves), wave w owns cols [32w, 32w+32).
// A/T tiles bf16 in LDS, 16B-granule XOR swizzle (g ^= row&7) -> conflict-free ds_read_b128.
// W fragments in VGPRs (loaded once per block from bf16 weights).
template <int FUSED, int SRCF32>
__global__ __launch_bounds__(256, 3) void layer_k(const void* __restrict__ Asrc,
                                                  const short* __restrict__ W1b,
                                                  const float* __restrict__ b1,
                                                  const short* __restrict__ W2b,
                                                  const float* __restrict__ b2,
                                                  const int* __restrict__ cnt,
                                                  const float* __restrict__ Hin,
                                                  float* __restrict__ outf,
                                                  unsigned short* __restrict__ outb, int nrows) {
    __shared__ short8 As[64 * 16];
    __shared__ short8 Ts[FUSED ? 64 * 16 : 16];
    __shared__ float dflag[64];
    int t = threadIdx.x;
    int rowbase = blockIdx.x * 64;

    // stage A tile
#pragma unroll
    for (int ch = 0; ch < 4; ++ch) {
        int flat = ch * 256 + t;  // 0..1023 : 64 rows x 16 granules(16B)
        int r = flat >> 4, g = flat & 15;
        int gr = rowbase + r;
        short8 frag = {0, 0, 0, 0, 0, 0, 0, 0};
        if (gr < nrows) {
            if (SRCF32) {
                const float4* src = (const float4*)Asrc;
                float4 a0 = src[(size_t)gr * 32 + g * 2];
                float4 a1 = src[(size_t)gr * 32 + g * 2 + 1];
                frag[0] = (short)cvbf(a0.x);
                frag[1] = (short)cvbf(a0.y);
                frag[2] = (short)cvbf(a0.z);
                frag[3] = (short)cvbf(a0.w);
                frag[4] = (short)cvbf(a1.x);
                frag[5] = (short)cvbf(a1.y);
                frag[6] = (short)cvbf(a1.z);
                frag[7] = (short)cvbf(a1.w);
            } else {
                frag = ((const short8*)Asrc)[(size_t)gr * 16 + g];
            }
        }
        As[r * 16 + (g ^ (r & 7))] = frag;
    }
    if (FUSED && t < 64) {
        int gr = rowbase + t;
        dflag[t] = (gr < nrows && cnt[gr] > 0) ? 1.0f : 0.0f;
    }

    int lane = t & 63;
    int w = t >> 6;  // 0..3
    int c0 = w * 32;
    int lrow = lane & 15;
    int lk = lane >> 4;  // 0..3
    int swz = lrow & 7;

    // W1 fragments: lane holds W[c0+ct*16+lrow][ks*32 + lk*8 .. +8)
    const short8* W1v = (const short8*)W1b;
    short8 bw[2][4];
#pragma unroll
    for (int ct = 0; ct < 2; ++ct)
#pragma unroll
        for (int ks = 0; ks < 4; ++ks)
            bw[ct][ks] = W1v[(size_t)(c0 + ct * 16 + lrow) * 16 + ks * 4 + lk];

    __syncthreads();

    f32x4 zero4 = {0.f, 0.f, 0.f, 0.f};
    f32x4 acc[4][2];
#pragma unroll
    for (int rt = 0; rt < 4; ++rt) {
        acc[rt][0] = zero4;
        acc[rt][1] = zero4;
    }
#pragma unroll
    for (int ks = 0; ks < 4; ++ks) {
        short8 a[4];
#pragma unroll
        for (int rt = 0; rt < 4; ++rt)
            a[rt] = As[(rt * 16 + lrow) * 16 + ((ks * 4 + lk) ^ swz)];
#pragma unroll
        for (int rt = 0; rt < 4; ++rt) {
            acc[rt][0] = __builtin_amdgcn_mfma_f32_16x16x32_bf16(a[rt], bw[0][ks], acc[rt][0], 0, 0, 0);
            acc[rt][1] = __builtin_amdgcn_mfma_f32_16x16x32_bf16(a[rt], bw[1][ks], acc[rt][1], 0, 0, 0);
        }
    }

    if (FUSED) {
        // W2 fragments (reuse pattern)
        const short8* W2v = (const short8*)W2b;
        short8 bw2[2][4];
#pragma unroll
        for (int ct = 0; ct < 2; ++ct)
#pragma unroll
            for (int ks = 0; ks < 4; ++ks)
                bw2[ct][ks] = W2v[(size_t)(c0 + ct * 16 + lrow) * 16 + ks * 4 + lk];

        float b1v[2] = {b1[c0 + lrow], b1[c0 + 16 + lrow]};
        short* TsS = (short*)Ts;
        // write T = acc + b1*(deg>0), bf16, swizzled
#pragma unroll
        for (int rt = 0; rt < 4; ++rt) {
#pragma unroll
            for (int ct = 0; ct < 2; ++ct) {
                int c = c0 + ct * 16 + lrow;
                int gh = c >> 3;
#pragma unroll
                for (int reg = 0; reg < 4; ++reg) {
                    int rl = rt * 16 + lk * 4 + reg;  // C/D: row=(lane>>4)*4+reg
                    float tv = acc[rt][ct][reg] + b1v[ct] * dflag[rl];
                    TsS[rl * 128 + ((gh ^ (rl & 7)) << 3) + (c & 7)] = (short)cvbf(tv);
                }
            }
        }
        __syncthreads();

        f32x4 acc2[4][2];
#pragma unroll
        for (int rt = 0; rt < 4; ++rt) {
            acc2[rt][0] = zero4;
            acc2[rt][1] = zero4;
        }
#pragma unroll
        for (int ks = 0; ks < 4; ++ks) {
            short8 a[4];
#pragma unroll
            for (int rt = 0; rt < 4; ++rt)
                a[rt] = Ts[(rt * 16 + lrow) * 16 + ((ks * 4 + lk) ^ swz)];
#pragma unroll
            for (int rt = 0; rt < 4; ++rt) {
                acc2[rt][0] = __builtin_amdgcn_mfma_f32_16x16x32_bf16(a[rt], bw2[0][ks], acc2[rt][0], 0, 0, 0);
                acc2[rt][1] = __builtin_amdgcn_mfma_f32_16x16x32_bf16(a[rt], bw2[1][ks], acc2[rt][1], 0, 0, 0);
            }
        }

        float b2v[2] = {b2[c0 + lrow], b2[c0 + 16 + lrow]};
#pragma unroll
        for (int rt = 0; rt < 4; ++rt) {
#pragma unroll
            for (int reg = 0; reg < 4; ++reg) {
                int grow = rowbase + rt * 16 + lk * 4 + reg;
                if (grow >= nrows) continue;
#pragma unroll
                for (int ct = 0; ct < 2; ++ct) {
                    int c = c0 + ct * 16 + lrow;
                    float o = Hin[(size_t)grow * 128 + c] +
                              fmaxf(acc2[rt][ct][reg] + b2v[ct], 0.f);
                    outf[(size_t)grow * 128 + c] = o;
                    outb[(size_t)grow * 128 + c] = cvbf(o);
                }
            }
        }
    } else {
        float b1v[2] = {b1[c0 + lrow], b1[c0 + 16 + lrow]};
#pragma unroll
        for (int rt = 0; rt < 4; ++rt) {
#pragma unroll
            for (int reg = 0; reg < 4; ++reg) {
                int grow = rowbase + rt * 16 + lk * 4 + reg;
                if (grow >= nrows) continue;
#pragma unroll
                for (int ct = 0; ct < 2; ++ct) {
                    int c = c0 + ct * 16 + lrow;
                    float o = acc[rt][ct][reg] + b1v[ct];
                    outf[(size_t)grow * 128 + c] = o;
                    outb[(size_t)grow * 128 + c] = cvbf(o);
                }
            }
        }
    }
}

extern "C" void kernel_launch(void* const* d_in, const int* in_sizes, int n_in,
                              void* d_out, int out_size, void* d_ws, size_t ws_size,
                              hipStream_t stream) {
    const float* x = (const float*)d_in[0];
    const float* Wi = (const float*)d_in[1];
    const float* bi = (const float*)d_in[2];
    const float* Wm = (const float*)d_in[3];
    const float* bm = (const float*)d_in[4];
    const float* Wu = (const float*)d_in[5];
    const float* bu = (const float*)d_in[6];
    const int* edge = (const int*)d_in[7];
    float* h = (float*)d_out;

    char* ws = (char*)d_ws;
    size_t off = 0;
    auto alloc = [&](size_t bytes) {
        void* p = ws + off;
        off += (bytes + 255) & ~(size_t)255;
        return p;
    };
    unsigned short* h_bf = (unsigned short*)alloc((size_t)N_NODES * D * 2);
    unsigned short* S_bf = (unsigned short*)alloc((size_t)N_NODES * D * 2);
    unsigned short* Wi_bf = (unsigned short*)alloc((size_t)D * D * 2);
    unsigned short* Wm_bf = (unsigned short*)alloc((size_t)NLAYERS * D * D * 2);
    unsigned short* Wu_bf = (unsigned short*)alloc((size_t)NLAYERS * D * D * 2);
    int* cnt = (int*)alloc((size_t)N_NODES * sizeof(int));
    int* rp = (int*)alloc((size_t)(N_NODES + 1) * sizeof(int));
    int* fill = (int*)alloc((size_t)N_NODES * sizeof(int));
    int* bsum = (int*)alloc(1024 * sizeof(int));
    int* col = (int*)alloc((size_t)N_EDGES * sizeof(int));

    const int scan_blocks = (N_NODES + 1023) / 1024;  // 98
    const int edge_blocks = (N_EDGES + 255) / 256;    // 2500
    const int gemm_blocks = (N_NODES + 63) / 64;      // 1563
    const int agg_blocks = (N_NODES + 3) / 4;         // 25000

    // CSR build
    hipMemsetAsync(cnt, 0, (size_t)N_NODES * sizeof(int), stream);
    count_kernel<<<edge_blocks, 256, 0, stream>>>(edge, cnt);
    scan_local<<<scan_blocks, 256, 0, stream>>>(cnt, rp, bsum);
    scan_bsums<<<1, 64, 0, stream>>>(bsum, scan_blocks);
    scan_add<<<scan_blocks, 256, 0, stream>>>(rp, fill, bsum);
    fill_kernel<<<edge_blocks, 256, 0, stream>>>(edge, fill, col);

    // weights -> bf16
    wconv<<<(D * D / 4 + 255) / 256, 256, 0, stream>>>(Wi, Wi_bf, D * D / 4);
    wconv<<<(NLAYERS * D * D / 4 + 255) / 256, 256, 0, stream>>>(Wm, Wm_bf, NLAYERS * D * D / 4);
    wconv<<<(NLAYERS * D * D / 4 + 255) / 256, 256, 0, stream>>>(Wu, Wu_bf, NLAYERS * D * D / 4);

    // input projection: h = x @ Wi^T + bi  (fp32 out + bf16 mirror)
    layer_k<0, 1><<<gemm_blocks, 256, 0, stream>>>(x, (const short*)Wi_bf, bi, nullptr, nullptr,
                                                   nullptr, nullptr, h, h_bf, N_NODES);

    for (int l = 0; l < NLAYERS; ++l) {
        agg_kernel<<<agg_blocks, 256, 0, stream>>>((const unsigned*)h_bf, rp, col,
                                                   (unsigned*)S_bf);
        layer_k<1, 0><<<gemm_blocks, 256, 0, stream>>>(
            S_bf, (const short*)(Wm_bf + (size_t)l * D * D), bm + (size_t)l * D,
            (const short*)(Wu_bf + (size_t)l * D * D), bu + (size_t)l * D, cnt, h, h, h_bf,
            N_NODES);
    }
}

// Round 4
// 399.905 us; speedup vs baseline: 3.0393x; 1.3829x over previous
//
#include <hip/hip_runtime.h>

#define N_NODES 100000
#define N_EDGES 640000
#define D 128
#define NLAYERS 4

typedef __attribute__((ext_vector_type(8))) short short8;
typedef __attribute__((ext_vector_type(4))) float f32x4;

// f32 -> bf16 with round-to-nearest-even
__device__ __forceinline__ unsigned short cvbf(float f) {
    unsigned u = __float_as_uint(f);
    return (unsigned short)((u + 0x7fffu + ((u >> 16) & 1u)) >> 16);
}

// ---------------- CSR build ----------------
__global__ void count_kernel(const int* __restrict__ edge, int* __restrict__ cnt) {
    int e = blockIdx.x * 256 + threadIdx.x;
    if (e < N_EDGES) atomicAdd(&cnt[edge[N_EDGES + e]], 1);
}

__global__ void scan_local(const int* __restrict__ cnt, int* __restrict__ rp,
                           int* __restrict__ bsum) {
    __shared__ int tsum[256];
    int t = threadIdx.x;
    int base = blockIdx.x * 1024 + t * 4;
    int v[4];
#pragma unroll
    for (int j = 0; j < 4; ++j) {
        int i = base + j;
        v[j] = (i < N_NODES) ? cnt[i] : 0;
    }
    int ts = v[0] + v[1] + v[2] + v[3];
    tsum[t] = ts;
    __syncthreads();
    for (int off = 1; off < 256; off <<= 1) {
        int add = (t >= off) ? tsum[t - off] : 0;
        __syncthreads();
        tsum[t] += add;
        __syncthreads();
    }
    int incl = tsum[t];
    int run = incl - ts;
#pragma unroll
    for (int j = 0; j < 4; ++j) {
        int i = base + j;
        if (i < N_NODES) rp[i] = run;
        run += v[j];
    }
    if (t == 255) bsum[blockIdx.x] = incl;
}

__global__ void scan_bsums(int* __restrict__ bsum, int nblocks) {
    if (threadIdx.x == 0 && blockIdx.x == 0) {
        int run = 0;
        for (int b = 0; b < nblocks; ++b) {
            int v = bsum[b];
            bsum[b] = run;
            run += v;
        }
    }
}

__global__ void scan_add(int* __restrict__ rp, int* __restrict__ fill,
                         const int* __restrict__ bsum) {
    int add = bsum[blockIdx.x];
    int base = blockIdx.x * 1024;
#pragma unroll
    for (int j = 0; j < 4; ++j) {
        int i = base + j * 256 + threadIdx.x;
        if (i < N_NODES) {
            int v = rp[i] + add;
            rp[i] = v;
            fill[i] = v;
        }
    }
    if (blockIdx.x == 0 && threadIdx.x == 0) rp[N_NODES] = N_EDGES;
}

__global__ void fill_kernel(const int* __restrict__ edge, int* __restrict__ fill,
                            int* __restrict__ col) {
    int e = blockIdx.x * 256 + threadIdx.x;
    if (e < N_EDGES) {
        int dst = edge[N_EDGES + e];
        int slot = atomicAdd(&fill[dst], 1);
        col[slot] = edge[e];
    }
}

// ---------------- weight fp32 -> bf16 ----------------
__global__ void wconv(const float* __restrict__ in, unsigned short* __restrict__ out, int n4) {
    int i = blockIdx.x * 256 + threadIdx.x;
    if (i < n4) {
        float4 v = ((const float4*)in)[i];
        ushort4 o;
        o.x = cvbf(v.x);
        o.y = cvbf(v.y);
        o.z = cvbf(v.z);
        o.w = cvbf(v.w);
        ((ushort4*)out)[i] = o;
    }
}

// ---------------- aggregation (bf16 gather): S_bf[v] = inv_deg * sum h_bf[src] ------
// 4 nodes per wave, interleaved -> 4 independent gathers in flight per wave.
// All CSR pointers wave-uniform (readfirstlane) -> scalar branches, s_load col prefetch.
__global__ __launch_bounds__(256) void agg_kernel(const unsigned* __restrict__ hb,
                                                  const int* __restrict__ rp,
                                                  const int* __restrict__ col,
                                                  unsigned* __restrict__ Sb) {
    int wv = __builtin_amdgcn_readfirstlane(threadIdx.x >> 6);
    int lane = threadIdx.x & 63;
    int v0 = blockIdx.x * 16 + wv * 4;
    if (v0 >= N_NODES) return;

    int r0 = __builtin_amdgcn_readfirstlane(rp[v0]);
    int r1 = __builtin_amdgcn_readfirstlane(rp[min(v0 + 1, N_NODES)]);
    int r2 = __builtin_amdgcn_readfirstlane(rp[min(v0 + 2, N_NODES)]);
    int r3 = __builtin_amdgcn_readfirstlane(rp[min(v0 + 3, N_NODES)]);
    int r4 = __builtin_amdgcn_readfirstlane(rp[min(v0 + 4, N_NODES)]);
    int d0 = r1 - r0, d1 = r2 - r1, d2 = r3 - r2, d3 = r4 - r3;
    int maxd = max(max(d0, d1), max(d2, d3));

    float ax0 = 0.f, ay0 = 0.f, ax1 = 0.f, ay1 = 0.f;
    float ax2 = 0.f, ay2 = 0.f, ax3 = 0.f, ay3 = 0.f;

    // prefetch col for j=0
    int u0 = 0, u1 = 0, u2 = 0, u3 = 0;
    if (0 < d0) u0 = col[r0];
    if (0 < d1) u1 = col[r1];
    if (0 < d2) u2 = col[r2];
    if (0 < d3) u3 = col[r3];

    for (int j = 0; j < maxd; ++j) {
        bool a0 = j < d0, a1 = j < d1, a2 = j < d2, a3 = j < d3;
        unsigned p0 = 0, p1 = 0, p2 = 0, p3 = 0;
        // issue all gathers first (independent -> 4 loads in flight)
        if (a0) p0 = hb[(size_t)u0 * 64 + lane];
        if (a1) p1 = hb[(size_t)u1 * 64 + lane];
        if (a2) p2 = hb[(size_t)u2 * 64 + lane];
        if (a3) p3 = hb[(size_t)u3 * 64 + lane];
        // prefetch next iteration's col indices (overlaps with gather latency)
        int jn = j + 1;
        if (jn < d0) u0 = col[r0 + jn];
        if (jn < d1) u1 = col[r1 + jn];
        if (jn < d2) u2 = col[r2 + jn];
        if (jn < d3) u3 = col[r3 + jn];
        // accumulate
        if (a0) { ax0 += __uint_as_float(p0 << 16); ay0 += __uint_as_float(p0 & 0xffff0000u); }
        if (a1) { ax1 += __uint_as_float(p1 << 16); ay1 += __uint_as_float(p1 & 0xffff0000u); }
        if (a2) { ax2 += __uint_as_float(p2 << 16); ay2 += __uint_as_float(p2 & 0xffff0000u); }
        if (a3) { ax3 += __uint_as_float(p3 << 16); ay3 += __uint_as_float(p3 & 0xffff0000u); }
    }

    {
        float inv = 1.0f / fmaxf((float)d0, 1.0f);
        Sb[(size_t)(v0 + 0) * 64 + lane] =
            ((unsigned)cvbf(ay0 * inv) << 16) | (unsigned)cvbf(ax0 * inv);
    }
    if (v0 + 1 < N_NODES) {
        float inv = 1.0f / fmaxf((float)d1, 1.0f);
        Sb[(size_t)(v0 + 1) * 64 + lane] =
            ((unsigned)cvbf(ay1 * inv) << 16) | (unsigned)cvbf(ax1 * inv);
    }
    if (v0 + 2 < N_NODES) {
        float inv = 1.0f / fmaxf((float)d2, 1.0f);
        Sb[(size_t)(v0 + 2) * 64 + lane] =
            ((unsigned)cvbf(ay2 * inv) << 16) | (unsigned)cvbf(ax2 * inv);
    }
    if (v0 + 3 < N_NODES) {
        float inv = 1.0f / fmaxf((float)d3, 1.0f);
        Sb[(size_t)(v0 + 3) * 64 + lane] =
            ((unsigned)cvbf(ay3 * inv) << 16) | (unsigned)cvbf(ax3 * inv);
    }
}

// ---------------- MFMA layer kernel ----------------
// FUSED=0: outf = A@W1^T + b1 (+ bf16 mirror)
// FUSED=1: T = A@W1^T + b1*(cnt>0); outf = Hin + relu(T@W2^T + b2)  (+ bf16 mirror)
template <int FUSED, int SRCF32>
__global__ __launch_bounds__(256, 3) void layer_k(const void* __restrict__ Asrc,
                                                  const short* __restrict__ W1b,
                                                  const float* __restrict__ b1,
                                                  const short* __restrict__ W2b,
                                                  const float* __restrict__ b2,
                                                  const int* __restrict__ cnt,
                                                  const float* __restrict__ Hin,
                                                  float* __restrict__ outf,
                                                  unsigned short* __restrict__ outb, int nrows) {
    __shared__ short8 As[64 * 16];
    __shared__ short8 Ts[FUSED ? 64 * 16 : 16];
    __shared__ float dflag[64];
    int t = threadIdx.x;
    int rowbase = blockIdx.x * 64;

    // stage A tile
#pragma unroll
    for (int ch = 0; ch < 4; ++ch) {
        int flat = ch * 256 + t;  // 0..1023 : 64 rows x 16 granules(16B)
        int r = flat >> 4, g = flat & 15;
        int gr = rowbase + r;
        short8 frag = {0, 0, 0, 0, 0, 0, 0, 0};
        if (gr < nrows) {
            if (SRCF32) {
                const float4* src = (const float4*)Asrc;
                float4 a0 = src[(size_t)gr * 32 + g * 2];
                float4 a1 = src[(size_t)gr * 32 + g * 2 + 1];
                frag[0] = (short)cvbf(a0.x);
                frag[1] = (short)cvbf(a0.y);
                frag[2] = (short)cvbf(a0.z);
                frag[3] = (short)cvbf(a0.w);
                frag[4] = (short)cvbf(a1.x);
                frag[5] = (short)cvbf(a1.y);
                frag[6] = (short)cvbf(a1.z);
                frag[7] = (short)cvbf(a1.w);
            } else {
                frag = ((const short8*)Asrc)[(size_t)gr * 16 + g];
            }
        }
        As[r * 16 + (g ^ (r & 7))] = frag;
    }
    if (FUSED && t < 64) {
        int gr = rowbase + t;
        dflag[t] = (gr < nrows && cnt[gr] > 0) ? 1.0f : 0.0f;
    }

    int lane = t & 63;
    int w = t >> 6;  // 0..3
    int c0 = w * 32;
    int lrow = lane & 15;
    int lk = lane >> 4;  // 0..3
    int swz = lrow & 7;

    // W1 fragments: lane holds W[c0+ct*16+lrow][ks*32 + lk*8 .. +8)
    const short8* W1v = (const short8*)W1b;
    short8 bw[2][4];
#pragma unroll
    for (int ct = 0; ct < 2; ++ct)
#pragma unroll
        for (int ks = 0; ks < 4; ++ks)
            bw[ct][ks] = W1v[(size_t)(c0 + ct * 16 + lrow) * 16 + ks * 4 + lk];

    __syncthreads();

    f32x4 zero4 = {0.f, 0.f, 0.f, 0.f};
    f32x4 acc[4][2];
#pragma unroll
    for (int rt = 0; rt < 4; ++rt) {
        acc[rt][0] = zero4;
        acc[rt][1] = zero4;
    }
#pragma unroll
    for (int ks = 0; ks < 4; ++ks) {
        short8 a[4];
#pragma unroll
        for (int rt = 0; rt < 4; ++rt)
            a[rt] = As[(rt * 16 + lrow) * 16 + ((ks * 4 + lk) ^ swz)];
#pragma unroll
        for (int rt = 0; rt < 4; ++rt) {
            acc[rt][0] = __builtin_amdgcn_mfma_f32_16x16x32_bf16(a[rt], bw[0][ks], acc[rt][0], 0, 0, 0);
            acc[rt][1] = __builtin_amdgcn_mfma_f32_16x16x32_bf16(a[rt], bw[1][ks], acc[rt][1], 0, 0, 0);
        }
    }

    if (FUSED) {
        const short8* W2v = (const short8*)W2b;
        short8 bw2[2][4];
#pragma unroll
        for (int ct = 0; ct < 2; ++ct)
#pragma unroll
            for (int ks = 0; ks < 4; ++ks)
                bw2[ct][ks] = W2v[(size_t)(c0 + ct * 16 + lrow) * 16 + ks * 4 + lk];

        float b1v[2] = {b1[c0 + lrow], b1[c0 + 16 + lrow]};
        short* TsS = (short*)Ts;
#pragma unroll
        for (int rt = 0; rt < 4; ++rt) {
#pragma unroll
            for (int ct = 0; ct < 2; ++ct) {
                int c = c0 + ct * 16 + lrow;
                int gh = c >> 3;
#pragma unroll
                for (int reg = 0; reg < 4; ++reg) {
                    int rl = rt * 16 + lk * 4 + reg;  // C/D: row=(lane>>4)*4+reg
                    float tv = acc[rt][ct][reg] + b1v[ct] * dflag[rl];
                    TsS[rl * 128 + ((gh ^ (rl & 7)) << 3) + (c & 7)] = (short)cvbf(tv);
                }
            }
        }
        __syncthreads();

        f32x4 acc2[4][2];
#pragma unroll
        for (int rt = 0; rt < 4; ++rt) {
            acc2[rt][0] = zero4;
            acc2[rt][1] = zero4;
        }
#pragma unroll
        for (int ks = 0; ks < 4; ++ks) {
            short8 a[4];
#pragma unroll
            for (int rt = 0; rt < 4; ++rt)
                a[rt] = Ts[(rt * 16 + lrow) * 16 + ((ks * 4 + lk) ^ swz)];
#pragma unroll
            for (int rt = 0; rt < 4; ++rt) {
                acc2[rt][0] = __builtin_amdgcn_mfma_f32_16x16x32_bf16(a[rt], bw2[0][ks], acc2[rt][0], 0, 0, 0);
                acc2[rt][1] = __builtin_amdgcn_mfma_f32_16x16x32_bf16(a[rt], bw2[1][ks], acc2[rt][1], 0, 0, 0);
            }
        }

        float b2v[2] = {b2[c0 + lrow], b2[c0 + 16 + lrow]};
#pragma unroll
        for (int rt = 0; rt < 4; ++rt) {
#pragma unroll
            for (int reg = 0; reg < 4; ++reg) {
                int grow = rowbase + rt * 16 + lk * 4 + reg;
                if (grow >= nrows) continue;
#pragma unroll
                for (int ct = 0; ct < 2; ++ct) {
                    int c = c0 + ct * 16 + lrow;
                    float o = Hin[(size_t)grow * 128 + c] +
                              fmaxf(acc2[rt][ct][reg] + b2v[ct], 0.f);
                    outf[(size_t)grow * 128 + c] = o;
                    outb[(size_t)grow * 128 + c] = cvbf(o);
                }
            }
        }
    } else {
        float b1v[2] = {b1[c0 + lrow], b1[c0 + 16 + lrow]};
#pragma unroll
        for (int rt = 0; rt < 4; ++rt) {
#pragma unroll
            for (int reg = 0; reg < 4; ++reg) {
                int grow = rowbase + rt * 16 + lk * 4 + reg;
                if (grow >= nrows) continue;
#pragma unroll
                for (int ct = 0; ct < 2; ++ct) {
                    int c = c0 + ct * 16 + lrow;
                    float o = acc[rt][ct][reg] + b1v[ct];
                    outf[(size_t)grow * 128 + c] = o;
                    outb[(size_t)grow * 128 + c] = cvbf(o);
                }
            }
        }
    }
}

extern "C" void kernel_launch(void* const* d_in, const int* in_sizes, int n_in,
                              void* d_out, int out_size, void* d_ws, size_t ws_size,
                              hipStream_t stream) {
    const float* x = (const float*)d_in[0];
    const float* Wi = (const float*)d_in[1];
    const float* bi = (const float*)d_in[2];
    const float* Wm = (const float*)d_in[3];
    const float* bm = (const float*)d_in[4];
    const float* Wu = (const float*)d_in[5];
    const float* bu = (const float*)d_in[6];
    const int* edge = (const int*)d_in[7];
    float* h = (float*)d_out;

    char* ws = (char*)d_ws;
    size_t off = 0;
    auto alloc = [&](size_t bytes) {
        void* p = ws + off;
        off += (bytes + 255) & ~(size_t)255;
        return p;
    };
    unsigned short* h_bf = (unsigned short*)alloc((size_t)N_NODES * D * 2);
    unsigned short* S_bf = (unsigned short*)alloc((size_t)N_NODES * D * 2);
    unsigned short* Wi_bf = (unsigned short*)alloc((size_t)D * D * 2);
    unsigned short* Wm_bf = (unsigned short*)alloc((size_t)NLAYERS * D * D * 2);
    unsigned short* Wu_bf = (unsigned short*)alloc((size_t)NLAYERS * D * D * 2);
    int* cnt = (int*)alloc((size_t)N_NODES * sizeof(int));
    int* rp = (int*)alloc((size_t)(N_NODES + 1) * sizeof(int));
    int* fill = (int*)alloc((size_t)N_NODES * sizeof(int));
    int* bsum = (int*)alloc(1024 * sizeof(int));
    int* col = (int*)alloc((size_t)N_EDGES * sizeof(int));

    const int scan_blocks = (N_NODES + 1023) / 1024;  // 98
    const int edge_blocks = (N_EDGES + 255) / 256;    // 2500
    const int gemm_blocks = (N_NODES + 63) / 64;      // 1563
    const int agg_blocks = (N_NODES + 15) / 16;       // 6250

    // CSR build
    hipMemsetAsync(cnt, 0, (size_t)N_NODES * sizeof(int), stream);
    count_kernel<<<edge_blocks, 256, 0, stream>>>(edge, cnt);
    scan_local<<<scan_blocks, 256, 0, stream>>>(cnt, rp, bsum);
    scan_bsums<<<1, 64, 0, stream>>>(bsum, scan_blocks);
    scan_add<<<scan_blocks, 256, 0, stream>>>(rp, fill, bsum);
    fill_kernel<<<edge_blocks, 256, 0, stream>>>(edge, fill, col);

    // weights -> bf16
    wconv<<<(D * D / 4 + 255) / 256, 256, 0, stream>>>(Wi, Wi_bf, D * D / 4);
    wconv<<<(NLAYERS * D * D / 4 + 255) / 256, 256, 0, stream>>>(Wm, Wm_bf, NLAYERS * D * D / 4);
    wconv<<<(NLAYERS * D * D / 4 + 255) / 256, 256, 0, stream>>>(Wu, Wu_bf, NLAYERS * D * D / 4);

    // input projection: h = x @ Wi^T + bi  (fp32 out + bf16 mirror)
    layer_k<0, 1><<<gemm_blocks, 256, 0, stream>>>(x, (const short*)Wi_bf, bi, nullptr, nullptr,
                                                   nullptr, nullptr, h, h_bf, N_NODES);

    for (int l = 0; l < NLAYERS; ++l) {
        agg_kernel<<<agg_blocks, 256, 0, stream>>>((const unsigned*)h_bf, rp, col,
                                                   (unsigned*)S_bf);
        layer_k<1, 0><<<gemm_blocks, 256, 0, stream>>>(
            S_bf, (const short*)(Wm_bf + (size_t)l * D * D), bm + (size_t)l * D,
            (const short*)(Wu_bf + (size_t)l * D * D), bu + (size_t)l * D, cnt, h, h, h_bf,
            N_NODES);
    }
}

// Round 5
// 373.318 us; speedup vs baseline: 3.2558x; 1.0712x over previous
//
#include <hip/hip_runtime.h>

#define N_NODES 100000
#define N_EDGES 640000
#define D 128
#define NLAYERS 4

typedef __attribute__((ext_vector_type(8))) short short8;
typedef __attribute__((ext_vector_type(4))) float f32x4;

// f32 -> bf16 with round-to-nearest-even
__device__ __forceinline__ unsigned short cvbf(float f) {
    unsigned u = __float_as_uint(f);
    return (unsigned short)((u + 0x7fffu + ((u >> 16) & 1u)) >> 16);
}

// ---------------- CSR build ----------------
__global__ void count_kernel(const int* __restrict__ edge, int* __restrict__ cnt) {
    int e = blockIdx.x * 256 + threadIdx.x;
    if (e < N_EDGES) atomicAdd(&cnt[edge[N_EDGES + e]], 1);
}

__global__ void scan_local(const int* __restrict__ cnt, int* __restrict__ rp,
                           int* __restrict__ bsum) {
    __shared__ int tsum[256];
    int t = threadIdx.x;
    int base = blockIdx.x * 1024 + t * 4;
    int v[4];
#pragma unroll
    for (int j = 0; j < 4; ++j) {
        int i = base + j;
        v[j] = (i < N_NODES) ? cnt[i] : 0;
    }
    int ts = v[0] + v[1] + v[2] + v[3];
    tsum[t] = ts;
    __syncthreads();
    for (int off = 1; off < 256; off <<= 1) {
        int add = (t >= off) ? tsum[t - off] : 0;
        __syncthreads();
        tsum[t] += add;
        __syncthreads();
    }
    int incl = tsum[t];
    int run = incl - ts;
#pragma unroll
    for (int j = 0; j < 4; ++j) {
        int i = base + j;
        if (i < N_NODES) rp[i] = run;
        run += v[j];
    }
    if (t == 255) bsum[blockIdx.x] = incl;
}

__global__ void scan_bsums(int* __restrict__ bsum, int nblocks) {
    if (threadIdx.x == 0 && blockIdx.x == 0) {
        int run = 0;
        for (int b = 0; b < nblocks; ++b) {
            int v = bsum[b];
            bsum[b] = run;
            run += v;
        }
    }
}

__global__ void scan_add(int* __restrict__ rp, int* __restrict__ fill,
                         const int* __restrict__ bsum) {
    int add = bsum[blockIdx.x];
    int base = blockIdx.x * 1024;
#pragma unroll
    for (int j = 0; j < 4; ++j) {
        int i = base + j * 256 + threadIdx.x;
        if (i < N_NODES) {
            int v = rp[i] + add;
            rp[i] = v;
            fill[i] = v;
        }
    }
    if (blockIdx.x == 0 && threadIdx.x == 0) rp[N_NODES] = N_EDGES;
}

__global__ void fill_kernel(const int* __restrict__ edge, int* __restrict__ fill,
                            int* __restrict__ col) {
    int e = blockIdx.x * 256 + threadIdx.x;
    if (e < N_EDGES) {
        int dst = edge[N_EDGES + e];
        int slot = atomicAdd(&fill[dst], 1);
        col[slot] = edge[e];
    }
}

// ---------------- weight fp32 -> bf16 ----------------
__global__ void wconv(const float* __restrict__ in, unsigned short* __restrict__ out, int n4) {
    int i = blockIdx.x * 256 + threadIdx.x;
    if (i < n4) {
        float4 v = ((const float4*)in)[i];
        ushort4 o;
        o.x = cvbf(v.x);
        o.y = cvbf(v.y);
        o.z = cvbf(v.z);
        o.w = cvbf(v.w);
        ((ushort4*)out)[i] = o;
    }
}

// ---------------- aggregation (bf16 gather): S_bf[v] = inv_deg * sum h_bf[src] ------
// 8 nodes per wave, interleaved in registers -> up to 8 independent gathers in flight.
__global__ __launch_bounds__(256) void agg_kernel(const unsigned* __restrict__ hb,
                                                  const int* __restrict__ rp,
                                                  const int* __restrict__ col,
                                                  unsigned* __restrict__ Sb) {
    constexpr int C = 8;
    int wv = __builtin_amdgcn_readfirstlane(threadIdx.x >> 6);
    int lane = threadIdx.x & 63;
    int v0 = (blockIdx.x * 4 + wv) * C;
    if (v0 >= N_NODES) return;

    int rb[C + 1];
#pragma unroll
    for (int i = 0; i <= C; ++i)
        rb[i] = __builtin_amdgcn_readfirstlane(rp[min(v0 + i, N_NODES)]);
    int d[C];
    int maxd = 0;
#pragma unroll
    for (int i = 0; i < C; ++i) {
        d[i] = rb[i + 1] - rb[i];
        maxd = max(maxd, d[i]);
    }

    float ax[C], ay[C];
    int u[C];
#pragma unroll
    for (int i = 0; i < C; ++i) {
        ax[i] = 0.f;
        ay[i] = 0.f;
        u[i] = 0;
    }
    // prefetch col for j=0
#pragma unroll
    for (int i = 0; i < C; ++i)
        if (0 < d[i]) u[i] = col[rb[i]];

    for (int j = 0; j < maxd; ++j) {
        unsigned p[C];
        // issue all active gathers first (independent -> in flight together)
#pragma unroll
        for (int i = 0; i < C; ++i) p[i] = (j < d[i]) ? hb[(size_t)u[i] * 64 + lane] : 0u;
        // prefetch next iteration's col indices (overlaps gather latency)
        int jn = j + 1;
#pragma unroll
        for (int i = 0; i < C; ++i)
            if (jn < d[i]) u[i] = col[rb[i] + jn];
        // accumulate
#pragma unroll
        for (int i = 0; i < C; ++i) {
            ax[i] += __uint_as_float(p[i] << 16);
            ay[i] += __uint_as_float(p[i] & 0xffff0000u);
        }
    }

#pragma unroll
    for (int i = 0; i < C; ++i) {
        if (v0 + i < N_NODES) {
            float inv = 1.0f / fmaxf((float)d[i], 1.0f);
            Sb[(size_t)(v0 + i) * 64 + lane] =
                ((unsigned)cvbf(ay[i] * inv) << 16) | (unsigned)cvbf(ax[i] * inv);
        }
    }
}

// ---------------- MFMA layer kernel ----------------
// FUSED=0: outf = A@W1^T + b1 (+ optional bf16 mirror)
// FUSED=1: T = A@W1^T + b1*(cnt>0); outf = Hin + relu(T@W2^T + b2)  (+ optional mirror)
// Epilogue: accumulators staged to a 32 KB fp32 LDS tile (bank-rotated
// col' = (col + ((row>>2)&3)*8) & 127 -> 2 lanes/bank = conflict-free), then fully
// coalesced float4 readout for Hin/outf/outb. LDS tile reuses the As+Ts region.
template <int FUSED, int SRCF32>
__global__ __launch_bounds__(256, 4) void layer_k(const void* __restrict__ Asrc,
                                                  const short* __restrict__ W1b,
                                                  const float* __restrict__ b1,
                                                  const short* __restrict__ W2b,
                                                  const float* __restrict__ b2,
                                                  const int* __restrict__ cnt,
                                                  const float* __restrict__ Hin,
                                                  float* __restrict__ outf,
                                                  unsigned short* __restrict__ outb, int nrows) {
    __shared__ __align__(16) char smem[32768];
    __shared__ float dflag[64];
    short8* As = (short8*)smem;                  // 16 KB
    short8* Ts = (short8*)(smem + 16384);        // 16 KB (FUSED only)
    float* Of = (float*)smem;                    // 32 KB fp32 output tile (after barrier)
    int t = threadIdx.x;
    int rowbase = blockIdx.x * 64;

    // stage A tile
#pragma unroll
    for (int ch = 0; ch < 4; ++ch) {
        int flat = ch * 256 + t;  // 0..1023 : 64 rows x 16 granules(16B)
        int r = flat >> 4, g = flat & 15;
        int gr = rowbase + r;
        short8 frag = {0, 0, 0, 0, 0, 0, 0, 0};
        if (gr < nrows) {
            if (SRCF32) {
                const float4* src = (const float4*)Asrc;
                float4 a0 = src[(size_t)gr * 32 + g * 2];
                float4 a1 = src[(size_t)gr * 32 + g * 2 + 1];
                frag[0] = (short)cvbf(a0.x);
                frag[1] = (short)cvbf(a0.y);
                frag[2] = (short)cvbf(a0.z);
                frag[3] = (short)cvbf(a0.w);
                frag[4] = (short)cvbf(a1.x);
                frag[5] = (short)cvbf(a1.y);
                frag[6] = (short)cvbf(a1.z);
                frag[7] = (short)cvbf(a1.w);
            } else {
                frag = ((const short8*)Asrc)[(size_t)gr * 16 + g];
            }
        }
        As[r * 16 + (g ^ (r & 7))] = frag;
    }
    if (FUSED && t < 64) {
        int gr = rowbase + t;
        dflag[t] = (gr < nrows && cnt[gr] > 0) ? 1.0f : 0.0f;
    }

    int lane = t & 63;
    int w = t >> 6;  // 0..3
    int c0 = w * 32;
    int lrow = lane & 15;
    int lk = lane >> 4;  // 0..3
    int swz = lrow & 7;

    // W1 fragments: lane holds W[c0+ct*16+lrow][ks*32 + lk*8 .. +8)
    const short8* W1v = (const short8*)W1b;
    short8 bw[2][4];
#pragma unroll
    for (int ct = 0; ct < 2; ++ct)
#pragma unroll
        for (int ks = 0; ks < 4; ++ks)
            bw[ct][ks] = W1v[(size_t)(c0 + ct * 16 + lrow) * 16 + ks * 4 + lk];

    __syncthreads();

    f32x4 zero4 = {0.f, 0.f, 0.f, 0.f};
    f32x4 acc[4][2];
#pragma unroll
    for (int rt = 0; rt < 4; ++rt) {
        acc[rt][0] = zero4;
        acc[rt][1] = zero4;
    }
#pragma unroll
    for (int ks = 0; ks < 4; ++ks) {
        short8 a[4];
#pragma unroll
        for (int rt = 0; rt < 4; ++rt)
            a[rt] = As[(rt * 16 + lrow) * 16 + ((ks * 4 + lk) ^ swz)];
#pragma unroll
        for (int rt = 0; rt < 4; ++rt) {
            acc[rt][0] = __builtin_amdgcn_mfma_f32_16x16x32_bf16(a[rt], bw[0][ks], acc[rt][0], 0, 0, 0);
            acc[rt][1] = __builtin_amdgcn_mfma_f32_16x16x32_bf16(a[rt], bw[1][ks], acc[rt][1], 0, 0, 0);
        }
    }

    if (FUSED) {
        const short8* W2v = (const short8*)W2b;
        short8 bw2[2][4];
#pragma unroll
        for (int ct = 0; ct < 2; ++ct)
#pragma unroll
            for (int ks = 0; ks < 4; ++ks)
                bw2[ct][ks] = W2v[(size_t)(c0 + ct * 16 + lrow) * 16 + ks * 4 + lk];

        float b1v[2] = {b1[c0 + lrow], b1[c0 + 16 + lrow]};
        short* TsS = (short*)Ts;
#pragma unroll
        for (int rt = 0; rt < 4; ++rt) {
#pragma unroll
            for (int ct = 0; ct < 2; ++ct) {
                int c = c0 + ct * 16 + lrow;
                int gh = c >> 3;
#pragma unroll
                for (int reg = 0; reg < 4; ++reg) {
                    int rl = rt * 16 + lk * 4 + reg;  // C/D: row=(lane>>4)*4+reg
                    float tv = acc[rt][ct][reg] + b1v[ct] * dflag[rl];
                    TsS[rl * 128 + ((gh ^ (rl & 7)) << 3) + (c & 7)] = (short)cvbf(tv);
                }
            }
        }
        __syncthreads();

        f32x4 acc2[4][2];
#pragma unroll
        for (int rt = 0; rt < 4; ++rt) {
            acc2[rt][0] = zero4;
            acc2[rt][1] = zero4;
        }
#pragma unroll
        for (int ks = 0; ks < 4; ++ks) {
            short8 a[4];
#pragma unroll
            for (int rt = 0; rt < 4; ++rt)
                a[rt] = Ts[(rt * 16 + lrow) * 16 + ((ks * 4 + lk) ^ swz)];
#pragma unroll
            for (int rt = 0; rt < 4; ++rt) {
                acc2[rt][0] = __builtin_amdgcn_mfma_f32_16x16x32_bf16(a[rt], bw2[0][ks], acc2[rt][0], 0, 0, 0);
                acc2[rt][1] = __builtin_amdgcn_mfma_f32_16x16x32_bf16(a[rt], bw2[1][ks], acc2[rt][1], 0, 0, 0);
            }
        }

        float b2v[2] = {b2[c0 + lrow], b2[c0 + 16 + lrow]};
        __syncthreads();  // As/Ts dead; Of takes over the region
#pragma unroll
        for (int rt = 0; rt < 4; ++rt) {
#pragma unroll
            for (int ct = 0; ct < 2; ++ct) {
                int c = c0 + ct * 16 + lrow;
#pragma unroll
                for (int reg = 0; reg < 4; ++reg) {
                    int row = rt * 16 + lk * 4 + reg;
                    Of[row * 128 + ((c + ((row >> 2) & 3) * 8) & 127)] =
                        acc2[rt][ct][reg] + b2v[ct];
                }
            }
        }
    } else {
        float b1v[2] = {b1[c0 + lrow], b1[c0 + 16 + lrow]};
        __syncthreads();  // As dead; Of takes over the region
#pragma unroll
        for (int rt = 0; rt < 4; ++rt) {
#pragma unroll
            for (int ct = 0; ct < 2; ++ct) {
                int c = c0 + ct * 16 + lrow;
#pragma unroll
                for (int reg = 0; reg < 4; ++reg) {
                    int row = rt * 16 + lk * 4 + reg;
                    Of[row * 128 + ((c + ((row >> 2) & 3) * 8) & 127)] =
                        acc[rt][ct][reg] + b1v[ct];
                }
            }
        }
    }
    __syncthreads();

    // coalesced float4 readout: residual+relu (FUSED) and stores
    const float4* Hin4 = (const float4*)Hin;
#pragma unroll
    for (int ch = 0; ch < 8; ++ch) {
        int f = ch * 256 + t;  // 0..2047 float4 slots (64 rows x 32)
        int row = f >> 5;
        int c4 = f & 31;
        int grow = rowbase + row;
        if (grow >= nrows) continue;
        int pc4 = (c4 + ((row >> 2) & 3) * 2) & 31;
        float4 v = *(const float4*)&Of[row * 128 + pc4 * 4];
        float4 o;
        if (FUSED) {
            float4 hv = Hin4[(size_t)grow * 32 + c4];
            o.x = hv.x + fmaxf(v.x, 0.f);
            o.y = hv.y + fmaxf(v.y, 0.f);
            o.z = hv.z + fmaxf(v.z, 0.f);
            o.w = hv.w + fmaxf(v.w, 0.f);
        } else {
            o = v;
        }
        ((float4*)outf)[(size_t)grow * 32 + c4] = o;
        if (outb) {
            ushort4 ob;
            ob.x = cvbf(o.x);
            ob.y = cvbf(o.y);
            ob.z = cvbf(o.z);
            ob.w = cvbf(o.w);
            ((ushort4*)outb)[(size_t)grow * 32 + c4] = ob;
        }
    }
}

extern "C" void kernel_launch(void* const* d_in, const int* in_sizes, int n_in,
                              void* d_out, int out_size, void* d_ws, size_t ws_size,
                              hipStream_t stream) {
    const float* x = (const float*)d_in[0];
    const float* Wi = (const float*)d_in[1];
    const float* bi = (const float*)d_in[2];
    const float* Wm = (const float*)d_in[3];
    const float* bm = (const float*)d_in[4];
    const float* Wu = (const float*)d_in[5];
    const float* bu = (const float*)d_in[6];
    const int* edge = (const int*)d_in[7];
    float* h = (float*)d_out;

    char* ws = (char*)d_ws;
    size_t off = 0;
    auto alloc = [&](size_t bytes) {
        void* p = ws + off;
        off += (bytes + 255) & ~(size_t)255;
        return p;
    };
    unsigned short* h_bf = (unsigned short*)alloc((size_t)N_NODES * D * 2);
    unsigned short* S_bf = (unsigned short*)alloc((size_t)N_NODES * D * 2);
    unsigned short* Wi_bf = (unsigned short*)alloc((size_t)D * D * 2);
    unsigned short* Wm_bf = (unsigned short*)alloc((size_t)NLAYERS * D * D * 2);
    unsigned short* Wu_bf = (unsigned short*)alloc((size_t)NLAYERS * D * D * 2);
    int* cnt = (int*)alloc((size_t)N_NODES * sizeof(int));
    int* rp = (int*)alloc((size_t)(N_NODES + 1) * sizeof(int));
    int* fill = (int*)alloc((size_t)N_NODES * sizeof(int));
    int* bsum = (int*)alloc(1024 * sizeof(int));
    int* col = (int*)alloc((size_t)N_EDGES * sizeof(int));

    const int scan_blocks = (N_NODES + 1023) / 1024;  // 98
    const int edge_blocks = (N_EDGES + 255) / 256;    // 2500
    const int gemm_blocks = (N_NODES + 63) / 64;      // 1563
    const int agg_blocks = (N_NODES + 31) / 32;       // 3125 (4 waves x 8 nodes)

    // CSR build
    hipMemsetAsync(cnt, 0, (size_t)N_NODES * sizeof(int), stream);
    count_kernel<<<edge_blocks, 256, 0, stream>>>(edge, cnt);
    scan_local<<<scan_blocks, 256, 0, stream>>>(cnt, rp, bsum);
    scan_bsums<<<1, 64, 0, stream>>>(bsum, scan_blocks);
    scan_add<<<scan_blocks, 256, 0, stream>>>(rp, fill, bsum);
    fill_kernel<<<edge_blocks, 256, 0, stream>>>(edge, fill, col);

    // weights -> bf16
    wconv<<<(D * D / 4 + 255) / 256, 256, 0, stream>>>(Wi, Wi_bf, D * D / 4);
    wconv<<<(NLAYERS * D * D / 4 + 255) / 256, 256, 0, stream>>>(Wm, Wm_bf, NLAYERS * D * D / 4);
    wconv<<<(NLAYERS * D * D / 4 + 255) / 256, 256, 0, stream>>>(Wu, Wu_bf, NLAYERS * D * D / 4);

    // input projection: h = x @ Wi^T + bi  (fp32 out + bf16 mirror)
    layer_k<0, 1><<<gemm_blocks, 256, 0, stream>>>(x, (const short*)Wi_bf, bi, nullptr, nullptr,
                                                   nullptr, nullptr, h, h_bf, N_NODES);

    for (int l = 0; l < NLAYERS; ++l) {
        agg_kernel<<<agg_blocks, 256, 0, stream>>>((const unsigned*)h_bf, rp, col,
                                                   (unsigned*)S_bf);
        // last layer: nobody consumes h_bf afterwards -> skip the mirror write
        unsigned short* mirror = (l == NLAYERS - 1) ? nullptr : h_bf;
        layer_k<1, 0><<<gemm_blocks, 256, 0, stream>>>(
            S_bf, (const short*)(Wm_bf + (size_t)l * D * D), bm + (size_t)l * D,
            (const short*)(Wu_bf + (size_t)l * D * D), bu + (size_t)l * D, cnt, h, h, mirror,
            N_NODES);
    }
}

// Round 7
// 350.654 us; speedup vs baseline: 3.4662x; 1.0646x over previous
//
#include <hip/hip_runtime.h>

#define N_NODES 100000
#define N_EDGES 640000
#define D 128
#define NLAYERS 4

typedef __attribute__((ext_vector_type(8))) short short8;
typedef __attribute__((ext_vector_type(4))) float f32x4;

// f32 -> bf16 with round-to-nearest-even
__device__ __forceinline__ unsigned short cvbf(float f) {
    unsigned u = __float_as_uint(f);
    return (unsigned short)((u + 0x7fffu + ((u >> 16) & 1u)) >> 16);
}

// ---------------- CSR build ----------------
__global__ void count_kernel(const int* __restrict__ edge, int* __restrict__ cnt) {
    int e = blockIdx.x * 256 + threadIdx.x;
    if (e < N_EDGES) atomicAdd(&cnt[edge[N_EDGES + e]], 1);
}

__global__ void scan_local(const int* __restrict__ cnt, int* __restrict__ rp,
                           int* __restrict__ bsum) {
    __shared__ int tsum[256];
    int t = threadIdx.x;
    int base = blockIdx.x * 1024 + t * 4;
    int v[4];
#pragma unroll
    for (int j = 0; j < 4; ++j) {
        int i = base + j;
        v[j] = (i < N_NODES) ? cnt[i] : 0;
    }
    int ts = v[0] + v[1] + v[2] + v[3];
    tsum[t] = ts;
    __syncthreads();
    for (int off = 1; off < 256; off <<= 1) {
        int add = (t >= off) ? tsum[t - off] : 0;
        __syncthreads();
        tsum[t] += add;
        __syncthreads();
    }
    int incl = tsum[t];
    int run = incl - ts;
#pragma unroll
    for (int j = 0; j < 4; ++j) {
        int i = base + j;
        if (i < N_NODES) rp[i] = run;
        run += v[j];
    }
    if (t == 255) bsum[blockIdx.x] = incl;
}

__global__ void scan_bsums(int* __restrict__ bsum, int nblocks) {
    if (threadIdx.x == 0 && blockIdx.x == 0) {
        int run = 0;
        for (int b = 0; b < nblocks; ++b) {
            int v = bsum[b];
            bsum[b] = run;
            run += v;
        }
    }
}

__global__ void scan_add(int* __restrict__ rp, int* __restrict__ fill,
                         const int* __restrict__ bsum) {
    int add = bsum[blockIdx.x];
    int base = blockIdx.x * 1024;
#pragma unroll
    for (int j = 0; j < 4; ++j) {
        int i = base + j * 256 + threadIdx.x;
        if (i < N_NODES) {
            int v = rp[i] + add;
            rp[i] = v;
            fill[i] = v;
        }
    }
    if (blockIdx.x == 0 && threadIdx.x == 0) rp[N_NODES] = N_EDGES;
}

__global__ void fill_kernel(const int* __restrict__ edge, int* __restrict__ fill,
                            int* __restrict__ col) {
    int e = blockIdx.x * 256 + threadIdx.x;
    if (e < N_EDGES) {
        int dst = edge[N_EDGES + e];
        int slot = atomicAdd(&fill[dst], 1);
        col[slot] = edge[e];
    }
}

// ---------------- weight fp32 -> bf16 ----------------
__global__ void wconv(const float* __restrict__ in, unsigned short* __restrict__ out, int n4) {
    int i = blockIdx.x * 256 + threadIdx.x;
    if (i < n4) {
        float4 v = ((const float4*)in)[i];
        ushort4 o;
        o.x = cvbf(v.x);
        o.y = cvbf(v.y);
        o.z = cvbf(v.z);
        o.w = cvbf(v.w);
        ((ushort4*)out)[i] = o;
    }
}

// ---------------- input projection: outf = x @ W1^T + b1 (+ bf16 mirror) ----------------
__global__ __launch_bounds__(256, 4) void proj_k(const float* __restrict__ Asrc,
                                                 const short* __restrict__ W1b,
                                                 const float* __restrict__ b1,
                                                 float* __restrict__ outf,
                                                 unsigned short* __restrict__ outb, int nrows) {
    __shared__ __align__(16) char smem[32768];
    short8* As = (short8*)smem;   // 16 KB
    float* Of = (float*)smem;     // 32 KB after barrier
    int t = threadIdx.x;
    int rowbase = blockIdx.x * 64;

#pragma unroll
    for (int ch = 0; ch < 4; ++ch) {
        int flat = ch * 256 + t;
        int r = flat >> 4, g = flat & 15;
        int gr = rowbase + r;
        short8 frag = {0, 0, 0, 0, 0, 0, 0, 0};
        if (gr < nrows) {
            const float4* src = (const float4*)Asrc;
            float4 a0 = src[(size_t)gr * 32 + g * 2];
            float4 a1 = src[(size_t)gr * 32 + g * 2 + 1];
            frag[0] = (short)cvbf(a0.x);
            frag[1] = (short)cvbf(a0.y);
            frag[2] = (short)cvbf(a0.z);
            frag[3] = (short)cvbf(a0.w);
            frag[4] = (short)cvbf(a1.x);
            frag[5] = (short)cvbf(a1.y);
            frag[6] = (short)cvbf(a1.z);
            frag[7] = (short)cvbf(a1.w);
        }
        As[r * 16 + (g ^ (r & 7))] = frag;
    }

    int lane = t & 63;
    int w = t >> 6;
    int c0 = w * 32;
    int lrow = lane & 15;
    int lk = lane >> 4;
    int swz = lrow & 7;

    const short8* W1v = (const short8*)W1b;
    short8 bw[2][4];
#pragma unroll
    for (int ct = 0; ct < 2; ++ct)
#pragma unroll
        for (int ks = 0; ks < 4; ++ks)
            bw[ct][ks] = W1v[(size_t)(c0 + ct * 16 + lrow) * 16 + ks * 4 + lk];

    __syncthreads();

    f32x4 zero4 = {0.f, 0.f, 0.f, 0.f};
    f32x4 acc[4][2];
#pragma unroll
    for (int rt = 0; rt < 4; ++rt) {
        acc[rt][0] = zero4;
        acc[rt][1] = zero4;
    }
#pragma unroll
    for (int ks = 0; ks < 4; ++ks) {
        short8 a[4];
#pragma unroll
        for (int rt = 0; rt < 4; ++rt)
            a[rt] = As[(rt * 16 + lrow) * 16 + ((ks * 4 + lk) ^ swz)];
#pragma unroll
        for (int rt = 0; rt < 4; ++rt) {
            acc[rt][0] = __builtin_amdgcn_mfma_f32_16x16x32_bf16(a[rt], bw[0][ks], acc[rt][0], 0, 0, 0);
            acc[rt][1] = __builtin_amdgcn_mfma_f32_16x16x32_bf16(a[rt], bw[1][ks], acc[rt][1], 0, 0, 0);
        }
    }

    float b1v[2] = {b1[c0 + lrow], b1[c0 + 16 + lrow]};
    __syncthreads();
#pragma unroll
    for (int rt = 0; rt < 4; ++rt) {
#pragma unroll
        for (int ct = 0; ct < 2; ++ct) {
            int c = c0 + ct * 16 + lrow;
#pragma unroll
            for (int reg = 0; reg < 4; ++reg) {
                int row = rt * 16 + lk * 4 + reg;
                Of[row * 128 + ((c + ((row >> 2) & 3) * 8) & 127)] = acc[rt][ct][reg] + b1v[ct];
            }
        }
    }
    __syncthreads();

#pragma unroll
    for (int ch = 0; ch < 8; ++ch) {
        int f = ch * 256 + t;
        int row = f >> 5;
        int c4 = f & 31;
        int grow = rowbase + row;
        if (grow >= nrows) continue;
        int pc4 = (c4 + ((row >> 2) & 3) * 2) & 31;
        float4 o = *(const float4*)&Of[row * 128 + pc4 * 4];
        ((float4*)outf)[(size_t)grow * 32 + c4] = o;
        ushort4 ob;
        ob.x = cvbf(o.x);
        ob.y = cvbf(o.y);
        ob.z = cvbf(o.z);
        ob.w = cvbf(o.w);
        ((ushort4*)outb)[(size_t)grow * 32 + c4] = ob;
    }
}

// ---------------- fused GNN layer ----------------
// Per block (64 nodes): gather-aggregate neighbors' hb_in rows directly into the
// swizzled As LDS tile (wave = 16 interleaved node-chains; CSR offsets/indices via
// wave-uniform addresses -> SGPRs), then T = As@W1^T + b1*(deg>0),
// out = Hin + relu(T@W2^T + b2) with LDS-staged coalesced epilogue.
// RACE NOTE: the bf16 mirror is written to hb_out != hb_in (ping-pong across
// layers) — gather reads only data completed at a prior kernel boundary.
__global__ __launch_bounds__(256, 4) void gnnlayer_k(
    const unsigned* __restrict__ hb_in, const int* __restrict__ rp, const int* __restrict__ col,
    const int* __restrict__ cnt, const short* __restrict__ W1b, const float* __restrict__ b1,
    const short* __restrict__ W2b, const float* __restrict__ b2, const float* __restrict__ Hin,
    float* __restrict__ outf, unsigned short* __restrict__ hb_out, int nrows) {
    __shared__ __align__(16) char smem[32768];
    __shared__ float dflag[64];
    short8* As = (short8*)smem;            // 16 KB aggregated A tile (bf16, swizzled)
    short8* Ts = (short8*)(smem + 16384);  // 16 KB T tile
    float* Of = (float*)smem;              // 32 KB fp32 output tile (after barrier)
    int t = threadIdx.x;
    int rowbase = blockIdx.x * 64;
    int lane = t & 63;
    int wv = __builtin_amdgcn_readfirstlane(t >> 6);  // 0..3

    // ---- gather-aggregate phase: this wave owns nodes nbase..nbase+16 ----
    {
        int nbase = rowbase + wv * 16;
        int rb[17];
#pragma unroll
        for (int i = 0; i <= 16; ++i)
            rb[i] = __builtin_amdgcn_readfirstlane(rp[min(nbase + i, N_NODES)]);
        int d[16];
        int maxd = 0;
#pragma unroll
        for (int i = 0; i < 16; ++i) {
            d[i] = rb[i + 1] - rb[i];
            maxd = max(maxd, d[i]);
        }

        float ax[16], ay[16];
        int u[16];
#pragma unroll
        for (int i = 0; i < 16; ++i) {
            ax[i] = 0.f;
            ay[i] = 0.f;
            u[i] = 0;
        }
#pragma unroll
        for (int i = 0; i < 16; ++i)
            if (0 < d[i]) u[i] = col[rb[i]];  // wave-uniform -> s_load

        for (int j = 0; j < maxd; ++j) {
            unsigned p[16];
            // issue all active gathers first (independent -> in flight together)
#pragma unroll
            for (int i = 0; i < 16; ++i)
                p[i] = (j < d[i]) ? hb_in[(size_t)u[i] * 64 + lane] : 0u;
            int jn = j + 1;
#pragma unroll
            for (int i = 0; i < 16; ++i)
                if (jn < d[i]) u[i] = col[rb[i] + jn];
#pragma unroll
            for (int i = 0; i < 16; ++i) {
                ax[i] += __uint_as_float(p[i] << 16);
                ay[i] += __uint_as_float(p[i] & 0xffff0000u);
            }
        }

        // write aggregated rows (bf16, inv_deg-scaled) into swizzled As tile.
        // lane holds cols {2*lane, 2*lane+1}: granule g = lane>>2, dword lane&3.
        unsigned* AsU = (unsigned*)As;
        int g = lane >> 2;
        int dw = lane & 3;
#pragma unroll
        for (int i = 0; i < 16; ++i) {
            float inv = 1.0f / fmaxf((float)d[i], 1.0f);
            unsigned pv = ((unsigned)cvbf(ay[i] * inv) << 16) | (unsigned)cvbf(ax[i] * inv);
            int r = wv * 16 + i;
            AsU[(r * 16 + (g ^ (r & 7))) * 4 + dw] = pv;
        }
    }
    if (t < 64) {
        int gr = rowbase + t;
        dflag[t] = (gr < nrows && cnt[gr] > 0) ? 1.0f : 0.0f;
    }

    int w = wv;
    int c0 = w * 32;
    int lrow = lane & 15;
    int lk = lane >> 4;
    int swz = lrow & 7;

    const short8* W1v = (const short8*)W1b;
    short8 bw[2][4];
#pragma unroll
    for (int ct = 0; ct < 2; ++ct)
#pragma unroll
        for (int ks = 0; ks < 4; ++ks)
            bw[ct][ks] = W1v[(size_t)(c0 + ct * 16 + lrow) * 16 + ks * 4 + lk];

    __syncthreads();

    f32x4 zero4 = {0.f, 0.f, 0.f, 0.f};
    f32x4 acc[4][2];
#pragma unroll
    for (int rt = 0; rt < 4; ++rt) {
        acc[rt][0] = zero4;
        acc[rt][1] = zero4;
    }
#pragma unroll
    for (int ks = 0; ks < 4; ++ks) {
        short8 a[4];
#pragma unroll
        for (int rt = 0; rt < 4; ++rt)
            a[rt] = As[(rt * 16 + lrow) * 16 + ((ks * 4 + lk) ^ swz)];
#pragma unroll
        for (int rt = 0; rt < 4; ++rt) {
            acc[rt][0] = __builtin_amdgcn_mfma_f32_16x16x32_bf16(a[rt], bw[0][ks], acc[rt][0], 0, 0, 0);
            acc[rt][1] = __builtin_amdgcn_mfma_f32_16x16x32_bf16(a[rt], bw[1][ks], acc[rt][1], 0, 0, 0);
        }
    }

    const short8* W2v = (const short8*)W2b;
    short8 bw2[2][4];
#pragma unroll
    for (int ct = 0; ct < 2; ++ct)
#pragma unroll
        for (int ks = 0; ks < 4; ++ks)
            bw2[ct][ks] = W2v[(size_t)(c0 + ct * 16 + lrow) * 16 + ks * 4 + lk];

    float b1v[2] = {b1[c0 + lrow], b1[c0 + 16 + lrow]};
    short* TsS = (short*)Ts;
#pragma unroll
    for (int rt = 0; rt < 4; ++rt) {
#pragma unroll
        for (int ct = 0; ct < 2; ++ct) {
            int c = c0 + ct * 16 + lrow;
            int gh = c >> 3;
#pragma unroll
            for (int reg = 0; reg < 4; ++reg) {
                int rl = rt * 16 + lk * 4 + reg;  // C/D: row=(lane>>4)*4+reg
                float tv = acc[rt][ct][reg] + b1v[ct] * dflag[rl];
                TsS[rl * 128 + ((gh ^ (rl & 7)) << 3) + (c & 7)] = (short)cvbf(tv);
            }
        }
    }
    __syncthreads();

    f32x4 acc2[4][2];
#pragma unroll
    for (int rt = 0; rt < 4; ++rt) {
        acc2[rt][0] = zero4;
        acc2[rt][1] = zero4;
    }
#pragma unroll
    for (int ks = 0; ks < 4; ++ks) {
        short8 a[4];
#pragma unroll
        for (int rt = 0; rt < 4; ++rt)
            a[rt] = Ts[(rt * 16 + lrow) * 16 + ((ks * 4 + lk) ^ swz)];
#pragma unroll
        for (int rt = 0; rt < 4; ++rt) {
            acc2[rt][0] = __builtin_amdgcn_mfma_f32_16x16x32_bf16(a[rt], bw2[0][ks], acc2[rt][0], 0, 0, 0);
            acc2[rt][1] = __builtin_amdgcn_mfma_f32_16x16x32_bf16(a[rt], bw2[1][ks], acc2[rt][1], 0, 0, 0);
        }
    }

    float b2v[2] = {b2[c0 + lrow], b2[c0 + 16 + lrow]};
    __syncthreads();  // As/Ts dead; Of takes over
#pragma unroll
    for (int rt = 0; rt < 4; ++rt) {
#pragma unroll
        for (int ct = 0; ct < 2; ++ct) {
            int c = c0 + ct * 16 + lrow;
#pragma unroll
            for (int reg = 0; reg < 4; ++reg) {
                int row = rt * 16 + lk * 4 + reg;
                Of[row * 128 + ((c + ((row >> 2) & 3) * 8) & 127)] = acc2[rt][ct][reg] + b2v[ct];
            }
        }
    }
    __syncthreads();

    const float4* Hin4 = (const float4*)Hin;
#pragma unroll
    for (int ch = 0; ch < 8; ++ch) {
        int f = ch * 256 + t;
        int row = f >> 5;
        int c4 = f & 31;
        int grow = rowbase + row;
        if (grow >= nrows) continue;
        int pc4 = (c4 + ((row >> 2) & 3) * 2) & 31;
        float4 v = *(const float4*)&Of[row * 128 + pc4 * 4];
        float4 hv = Hin4[(size_t)grow * 32 + c4];
        float4 o;
        o.x = hv.x + fmaxf(v.x, 0.f);
        o.y = hv.y + fmaxf(v.y, 0.f);
        o.z = hv.z + fmaxf(v.z, 0.f);
        o.w = hv.w + fmaxf(v.w, 0.f);
        ((float4*)outf)[(size_t)grow * 32 + c4] = o;
        if (hb_out) {
            ushort4 ob;
            ob.x = cvbf(o.x);
            ob.y = cvbf(o.y);
            ob.z = cvbf(o.z);
            ob.w = cvbf(o.w);
            ((ushort4*)hb_out)[(size_t)grow * 32 + c4] = ob;
        }
    }
}

extern "C" void kernel_launch(void* const* d_in, const int* in_sizes, int n_in,
                              void* d_out, int out_size, void* d_ws, size_t ws_size,
                              hipStream_t stream) {
    const float* x = (const float*)d_in[0];
    const float* Wi = (const float*)d_in[1];
    const float* bi = (const float*)d_in[2];
    const float* Wm = (const float*)d_in[3];
    const float* bm = (const float*)d_in[4];
    const float* Wu = (const float*)d_in[5];
    const float* bu = (const float*)d_in[6];
    const int* edge = (const int*)d_in[7];
    float* h = (float*)d_out;

    char* ws = (char*)d_ws;
    size_t off = 0;
    auto alloc = [&](size_t bytes) {
        void* p = ws + off;
        off += (bytes + 255) & ~(size_t)255;
        return p;
    };
    // ping-pong bf16 mirrors of h (avoids cross-block RAW race in fused layers)
    unsigned short* hbuf[2];
    hbuf[0] = (unsigned short*)alloc((size_t)N_NODES * D * 2);
    hbuf[1] = (unsigned short*)alloc((size_t)N_NODES * D * 2);
    unsigned short* Wi_bf = (unsigned short*)alloc((size_t)D * D * 2);
    unsigned short* Wm_bf = (unsigned short*)alloc((size_t)NLAYERS * D * D * 2);
    unsigned short* Wu_bf = (unsigned short*)alloc((size_t)NLAYERS * D * D * 2);
    int* cnt = (int*)alloc((size_t)N_NODES * sizeof(int));
    int* rp = (int*)alloc((size_t)(N_NODES + 1) * sizeof(int));
    int* fill = (int*)alloc((size_t)N_NODES * sizeof(int));
    int* bsum = (int*)alloc(1024 * sizeof(int));
    int* col = (int*)alloc((size_t)N_EDGES * sizeof(int));

    const int scan_blocks = (N_NODES + 1023) / 1024;  // 98
    const int edge_blocks = (N_EDGES + 255) / 256;    // 2500
    const int gemm_blocks = (N_NODES + 63) / 64;      // 1563

    // CSR build
    hipMemsetAsync(cnt, 0, (size_t)N_NODES * sizeof(int), stream);
    count_kernel<<<edge_blocks, 256, 0, stream>>>(edge, cnt);
    scan_local<<<scan_blocks, 256, 0, stream>>>(cnt, rp, bsum);
    scan_bsums<<<1, 64, 0, stream>>>(bsum, scan_blocks);
    scan_add<<<scan_blocks, 256, 0, stream>>>(rp, fill, bsum);
    fill_kernel<<<edge_blocks, 256, 0, stream>>>(edge, fill, col);

    // weights -> bf16
    wconv<<<(D * D / 4 + 255) / 256, 256, 0, stream>>>(Wi, Wi_bf, D * D / 4);
    wconv<<<(NLAYERS * D * D / 4 + 255) / 256, 256, 0, stream>>>(Wm, Wm_bf, NLAYERS * D * D / 4);
    wconv<<<(NLAYERS * D * D / 4 + 255) / 256, 256, 0, stream>>>(Wu, Wu_bf, NLAYERS * D * D / 4);

    // input projection: h = x @ Wi^T + bi  (fp32 out + bf16 mirror into hbuf[0])
    proj_k<<<gemm_blocks, 256, 0, stream>>>(x, (const short*)Wi_bf, bi, h, hbuf[0], N_NODES);

    for (int l = 0; l < NLAYERS; ++l) {
        // read mirror hbuf[l&1], write mirror hbuf[(l+1)&1] (none on last layer)
        unsigned short* mirror = (l == NLAYERS - 1) ? nullptr : hbuf[(l + 1) & 1];
        gnnlayer_k<<<gemm_blocks, 256, 0, stream>>>(
            (const unsigned*)hbuf[l & 1], rp, col, cnt,
            (const short*)(Wm_bf + (size_t)l * D * D), bm + (size_t)l * D,
            (const short*)(Wu_bf + (size_t)l * D * D), bu + (size_t)l * D, h, h, mirror,
            N_NODES);
    }
}